// Round 1
// baseline (836.044 us; speedup 1.0000x reference)
//
#include <hip/hip_runtime.h>

// ---------------------------------------------------------------------------
// EnterpriseGNN: 3-layer GCN on MI355X.
//   h1 = relu(GCNConv(x, W1, b1));  h2 = relu(GCNConv(h1, W2, b2));
//   out = h2 @ Wout + bout
// GCNConv(x,W,b)[i] = dinv[i] * ( sum_{e:dst=i} w_e * g[src_e] + g[i] ) + b
//   where g = dinv .* (x@W),  dinv = rsqrt(deg+1), deg = sum_{e:dst=i} w_e.
// deg/dinv shared across both conv layers (same graph + weights).
// ---------------------------------------------------------------------------

#define BLK 256

__global__ void deg_kernel(const int* __restrict__ dst,
                           const float* __restrict__ w,
                           float* __restrict__ deg, int E) {
    int e = blockIdx.x * blockDim.x + threadIdx.x;
    if (e < E) atomicAdd(&deg[dst[e]], w[e]);
}

__global__ void dinv_kernel(float* __restrict__ deg, int N) {
    int i = blockIdx.x * blockDim.x + threadIdx.x;
    if (i < N) deg[i] = rsqrtf(deg[i] + 1.0f);  // in-place deg -> dinv
}

// g1[i][j] = dinv[i] * sum_k x[i][k] * W1[k][j]   (128 -> 32)
__global__ void gemm1_kernel(const float* __restrict__ x,
                             const float* __restrict__ W1,
                             const float* __restrict__ dinv,
                             float* __restrict__ g1, int N) {
    __shared__ float sW[128 * 32];   // 16 KB
    __shared__ float sx[8][128];     // 4 KB
    for (int i = threadIdx.x; i < 128 * 32; i += BLK) sW[i] = W1[i];
    int node0 = blockIdx.x * 8;
    for (int i = threadIdx.x; i < 8 * 128; i += BLK) {
        int r = i >> 7, c = i & 127;
        int n = node0 + r;
        sx[r][c] = (n < N) ? x[(long long)n * 128 + c] : 0.f;
    }
    __syncthreads();
    int local = threadIdx.x >> 5;     // node within block (0..7)
    int j = threadIdx.x & 31;         // output feature
    int n = node0 + local;
    if (n < N) {
        float acc = 0.f;
#pragma unroll 16
        for (int k = 0; k < 128; k++) acc += sx[local][k] * sW[k * 32 + j];
        g1[n * 32 + j] = acc * dinv[n];
    }
}

// agg[dst][f] += w * g[src][f] ; one thread per (edge, feature)
template <int F>
__global__ void edge_agg_kernel(const int* __restrict__ src,
                                const int* __restrict__ dst,
                                const float* __restrict__ w,
                                const float* __restrict__ g,
                                float* __restrict__ agg, int E) {
    unsigned idx = blockIdx.x * blockDim.x + threadIdx.x;
    unsigned total = (unsigned)E * F;
    if (idx >= total) return;
    unsigned e = idx / F;          // F is power of two -> shift
    unsigned f = idx & (F - 1);
    int s = __ldg(&src[e]);
    int d = __ldg(&dst[e]);
    float we = __ldg(&w[e]);
    atomicAdd(&agg[(unsigned)d * F + f], we * g[(unsigned)s * F + f]);
}

// in1 = relu(dinv*(agg1+g1)+b1);  g2[i][j] = dinv[i] * sum_k in1[i][k]*W2[k][j]
__global__ void layer2_kernel(const float* __restrict__ agg1,
                              const float* __restrict__ g1,
                              const float* __restrict__ dinv,
                              const float* __restrict__ b1,
                              const float* __restrict__ W2,
                              float* __restrict__ g2, int N) {
    __shared__ float sW[32 * 16];
    __shared__ float sin_[16][32];
    for (int i = threadIdx.x; i < 32 * 16; i += BLK) sW[i] = W2[i];
    int node0 = blockIdx.x * 16;
    for (int i = threadIdx.x; i < 16 * 32; i += BLK) {
        int r = i >> 5, c = i & 31;
        int n = node0 + r;
        float v = 0.f;
        if (n < N) {
            float di = dinv[n];
            v = fmaxf(di * (agg1[n * 32 + c] + g1[n * 32 + c]) + b1[c], 0.f);
        }
        sin_[r][c] = v;
    }
    __syncthreads();
    int local = threadIdx.x >> 4;   // 0..15
    int j = threadIdx.x & 15;
    int n = node0 + local;
    if (n < N) {
        float acc = 0.f;
#pragma unroll
        for (int k = 0; k < 32; k++) acc += sin_[local][k] * sW[k * 16 + j];
        g2[n * 16 + j] = acc * dinv[n];
    }
}

// out[i] = relu(dinv*(agg2+g2)+b2) @ Wout + bout
__global__ void final_kernel(const float* __restrict__ agg2,
                             const float* __restrict__ g2,
                             const float* __restrict__ dinv,
                             const float* __restrict__ b2,
                             const float* __restrict__ Wout,
                             const float* __restrict__ bout,
                             float* __restrict__ out, int N) {
    int n = blockIdx.x * blockDim.x + threadIdx.x;
    if (n >= N) return;
    float di = dinv[n];
    float o0 = bout[0], o1 = bout[1], o2 = bout[2];
#pragma unroll
    for (int k = 0; k < 16; k++) {
        float v = fmaxf(di * (agg2[n * 16 + k] + g2[n * 16 + k]) + b2[k], 0.f);
        o0 += v * Wout[k * 3 + 0];
        o1 += v * Wout[k * 3 + 1];
        o2 += v * Wout[k * 3 + 2];
    }
    out[n * 3 + 0] = o0;
    out[n * 3 + 1] = o1;
    out[n * 3 + 2] = o2;
}

extern "C" void kernel_launch(void* const* d_in, const int* in_sizes, int n_in,
                              void* d_out, int out_size, void* d_ws, size_t ws_size,
                              hipStream_t stream) {
    const float* x   = (const float*)d_in[0];
    const int* ei    = (const int*)d_in[1];   // [2, E]: row0 = src, row1 = dst
    const float* ew  = (const float*)d_in[2];
    const float* W1  = (const float*)d_in[3];
    const float* b1  = (const float*)d_in[4];
    const float* W2  = (const float*)d_in[5];
    const float* b2  = (const float*)d_in[6];
    const float* Wout = (const float*)d_in[7];
    const float* bout = (const float*)d_in[8];
    float* out = (float*)d_out;

    const int N = in_sizes[0] / 128;
    const int E = in_sizes[2];
    const int* src = ei;
    const int* dst = ei + E;

    // workspace layout (floats):
    //  [0, N)        deg -> dinv (in place)
    //  [N, 33N)      agg1 (N x 32)
    //  [33N, 49N)    agg2 (N x 16)
    //  [49N, 81N)    g1   (N x 32)
    //  [81N, 97N)    g2   (N x 16)
    float* ws   = (float*)d_ws;
    float* deg  = ws;              // also dinv after dinv_kernel
    float* agg1 = ws + (size_t)N;
    float* agg2 = ws + (size_t)33 * N;
    float* g1   = ws + (size_t)49 * N;
    float* g2   = ws + (size_t)81 * N;

    // zero deg + agg1 + agg2 (first 49N floats) — ws is poisoned each call
    hipMemsetAsync(ws, 0, (size_t)49 * N * sizeof(float), stream);

    deg_kernel<<<(E + BLK - 1) / BLK, BLK, 0, stream>>>(dst, ew, deg, E);
    dinv_kernel<<<(N + BLK - 1) / BLK, BLK, 0, stream>>>(deg, N);

    gemm1_kernel<<<(N + 7) / 8, BLK, 0, stream>>>(x, W1, deg, g1, N);

    {
        unsigned total = (unsigned)E * 32u;
        edge_agg_kernel<32><<<(total + BLK - 1) / BLK, BLK, 0, stream>>>(
            src, dst, ew, g1, agg1, E);
    }

    layer2_kernel<<<(N + 15) / 16, BLK, 0, stream>>>(agg1, g1, deg, b1, W2, g2, N);

    {
        unsigned total = (unsigned)E * 16u;
        edge_agg_kernel<16><<<(total + BLK - 1) / BLK, BLK, 0, stream>>>(
            src, dst, ew, g2, agg2, E);
    }

    final_kernel<<<(N + BLK - 1) / BLK, BLK, 0, stream>>>(
        agg2, g2, deg, b2, Wout, bout, out, N);
}